// Round 7
// baseline (665.615 us; speedup 1.0000x reference)
//
#include <hip/hip_runtime.h>
#include <hip/hip_bf16.h>

#define PAD 16        // pad each CSR segment to a multiple of 16 edges
#define NBKT_MAX 512  // buckets of 512 dests (dest >> 9)

typedef __attribute__((ext_vector_type(8))) short short8;
typedef __attribute__((ext_vector_type(4))) float float4v;
typedef unsigned int __attribute__((ext_vector_type(4))) uint4v;  // nt-builtin-legal 16B

__device__ __forceinline__ short8 s8(uint4v v) {
    union { uint4v u; short8 s; } x; x.u = v; return x.s;
}

__device__ __forceinline__ int pad_up(int v) { return (v + (PAD - 1)) & ~(PAD - 1); }

// ---------------- bucketed CSR build ----------------
// pairs packed: (src << 9) | (dst & 511)  [src < 2^17, bucket-local dst 9 bits]

// per-block histogram of dest buckets; blockHist[bucket][block]; int4 reads
__global__ __launch_bounds__(256) void hist_kernel(const int* __restrict__ col,
                                                   int* __restrict__ blockHist, int E, int nbkt) {
    __shared__ int h[NBKT_MAX];
    for (int i = threadIdx.x; i < nbkt; i += 256) h[i] = 0;
    __syncthreads();
    int E4 = E >> 2;
    int stride = gridDim.x * 256;
    for (int i = blockIdx.x * 256 + threadIdx.x; i < E4; i += stride) {
        int4 c = ((const int4*)col)[i];
        atomicAdd(&h[c.x >> 9], 1);
        atomicAdd(&h[c.y >> 9], 1);
        atomicAdd(&h[c.z >> 9], 1);
        atomicAdd(&h[c.w >> 9], 1);
    }
    if (blockIdx.x == 0)
        for (int e = E4 * 4 + threadIdx.x; e < E; e += 256) atomicAdd(&h[col[e] >> 9], 1);
    __syncthreads();
    for (int i = threadIdx.x; i < nbkt; i += 256) blockHist[i * 256 + blockIdx.x] = h[i];
}

// per-bucket exclusive scan across the 256 blocks; bktTot[bucket] = total
__global__ __launch_bounds__(256) void bscan_kernel(int* __restrict__ blockHist,
                                                    int* __restrict__ bktTot, int nbkt) {
    __shared__ int a[256], b[256];
    int bkt = blockIdx.x;
    int t = threadIdx.x;
    int v = blockHist[bkt * 256 + t];
    a[t] = v;
    __syncthreads();
    int* s = a; int* d = b;
    for (int off = 1; off < 256; off <<= 1) {
        int x = s[t];
        if (t >= off) x += s[t - off];
        d[t] = x;
        __syncthreads();
        int* tmp = s; s = d; d = tmp;
    }
    blockHist[bkt * 256 + t] = s[t] - v;
    if (t == 255) bktTot[bkt] = s[t];
}

// generic single-block exclusive scan over n<=256 ints
__global__ void scan_small(const int* __restrict__ in, int* __restrict__ outp, int n) {
    __shared__ int a[256], b[256];
    int t = threadIdx.x;
    int v = t < n ? in[t] : 0;
    a[t] = v;
    __syncthreads();
    int* s = a; int* d = b;
    for (int off = 1; off < 256; off <<= 1) {
        int x = s[t];
        if (t >= off) x += s[t - off];
        d[t] = x;
        __syncthreads();
        int* tmp = s; s = d; d = tmp;
    }
    if (t < n) outp[t] = s[t] - v;
}

// scatter packed (src,dst) into bucket-grouped array; per-(block,bucket) runs contiguous
__global__ __launch_bounds__(256) void scatter_kernel(const int* __restrict__ row,
                                                      const int* __restrict__ col,
                                                      const int* __restrict__ blockHist,
                                                      const int* __restrict__ bktOff,
                                                      unsigned int* __restrict__ pairs,
                                                      int E, int nbkt) {
    __shared__ int cur[NBKT_MAX];
    for (int i = threadIdx.x; i < nbkt; i += 256)
        cur[i] = bktOff[i] + blockHist[i * 256 + blockIdx.x];
    __syncthreads();
    int E4 = E >> 2;
    int stride = gridDim.x * 256;
    for (int i = blockIdx.x * 256 + threadIdx.x; i < E4; i += stride) {
        int4 c = ((const int4*)col)[i];
        int4 r = ((const int4*)row)[i];
        int p0 = atomicAdd(&cur[c.x >> 9], 1);
        pairs[p0] = ((unsigned int)r.x << 9) | (unsigned int)(c.x & 511);
        int p1 = atomicAdd(&cur[c.y >> 9], 1);
        pairs[p1] = ((unsigned int)r.y << 9) | (unsigned int)(c.y & 511);
        int p2 = atomicAdd(&cur[c.z >> 9], 1);
        pairs[p2] = ((unsigned int)r.z << 9) | (unsigned int)(c.z & 511);
        int p3 = atomicAdd(&cur[c.w >> 9], 1);
        pairs[p3] = ((unsigned int)r.w << 9) | (unsigned int)(c.w & 511);
    }
    if (blockIdx.x == 0)
        for (int e = E4 * 4 + threadIdx.x; e < E; e += 256) {
            int dn = col[e];
            int p = atomicAdd(&cur[dn >> 9], 1);
            pairs[p] = ((unsigned int)row[e] << 9) | (unsigned int)(dn & 511);
        }
}

// fused: per-bucket degree histogram -> deg/dinv/dinv2/sdeg AND chunkSum (padded sums)
__global__ __launch_bounds__(256) void deg_scanA_kernel(
        const unsigned int* __restrict__ pairs, const int* __restrict__ bktOff,
        const int* __restrict__ bktTot,
        int* __restrict__ deg, float* __restrict__ dinv, float* __restrict__ dinv2,
        float* __restrict__ sdeg, int* __restrict__ chunkSum, int N) {
    __shared__ int cnt[512];
    __shared__ int wsum[4];
    int b = blockIdx.x, d0 = b << 9;
    int t = threadIdx.x;
    for (int i = t; i < 512; i += 256) cnt[i] = 0;
    __syncthreads();
    int lo = bktOff[b], hi = lo + bktTot[b];
    for (int p = lo + t; p < hi; p += 256)
        atomicAdd(&cnt[pairs[p] & 511u], 1);
    __syncthreads();
    int sA = 0;
    for (int i = t; i < 512; i += 256) {
        int c = cnt[i];
        sA += pad_up(c);
        int d = d0 + i;
        if (d < N) {
            deg[d] = c;
            float v = c > 0 ? rsqrtf((float)c) : 0.0f;
            dinv[d] = v;
            dinv2[d] = v * v;
            sdeg[d] = c > 0 ? sqrtf((float)c) : 0.0f;
        }
    }
    for (int o = 32; o > 0; o >>= 1) sA += __shfl_down(sA, o, 64);
    if ((t & 63) == 0) wsum[t >> 6] = sA;
    __syncthreads();
    if (t == 0) chunkSum[b] = wsum[0] + wsum[1] + wsum[2] + wsum[3];
}

__global__ void scan_phaseC(const int* __restrict__ deg, const int* __restrict__ chunkOff,
                            int* __restrict__ rowptr, int N) {
    __shared__ int a[512], b[512];
    int t = threadIdx.x;
    int idx = blockIdx.x * 512 + t;
    int v = idx < N ? pad_up(deg[idx]) : 0;
    a[t] = v;
    __syncthreads();
    int* s = a; int* d = b;
    for (int off = 1; off < 512; off <<= 1) {
        int x = s[t];
        if (t >= off) x += s[t - off];
        d[t] = x;
        __syncthreads();
        int* tmp = s; s = d; d = tmp;
    }
    if (idx < N) rowptr[idx] = chunkOff[blockIdx.x] + s[t] - v;
    if (idx == N - 1) rowptr[N] = chunkOff[blockIdx.x] + s[t];
}

// per-bucket: scatter srcs into the bucket's contiguous CSR window (L2-resident),
// then fill pad slots (cur[i] -> rowptr[d+1]) while the window is hot.
__global__ __launch_bounds__(256) void cluster_kernel(const unsigned int* __restrict__ pairs,
                                                      const int* __restrict__ bktOff,
                                                      const int* __restrict__ bktTot,
                                                      const int* __restrict__ rowptr,
                                                      int* __restrict__ srcs, int N) {
    __shared__ int cur[512];
    int b = blockIdx.x;
    int d0 = b << 9;
    for (int i = threadIdx.x; i < 512; i += 256) {
        int d = d0 + i;
        cur[i] = (d < N) ? rowptr[d] : 0;
    }
    __syncthreads();
    int lo = bktOff[b], hi = lo + bktTot[b];
    for (int p = lo + threadIdx.x; p < hi; p += 256) {
        unsigned int e = pairs[p];
        int pos = atomicAdd(&cur[e & 511u], 1);
        srcs[pos] = (int)(e >> 9);
    }
    __syncthreads();
    for (int i = threadIdx.x; i < 512; i += 256) {
        int d = d0 + i;
        if (d < N) {
            int p = cur[i];              // == rowptr[d] + deg[d]
            int p1 = rowptr[d + 1];
            for (; p < p1; ++p) srcs[p] = N;
        }
    }
}

// ---------------- weight conversion / g init ----------------

// Convert w1 (11) + w2 (4) + wc (1) into MFMA B-fragment order, bf16.
__global__ void wcvt_kernel(const float* __restrict__ w1, const float* __restrict__ w2,
                            const float* __restrict__ wc, __hip_bfloat16* __restrict__ wf) {
    int idx = blockIdx.x * blockDim.x + threadIdx.x;
    if (idx >= 16 * 4096) return;
    int g = idx >> 12, r = idx & 4095;
    int j = r & 7, lane = (r >> 3) & 63, u = (r >> 9) & 3, t = r >> 11;
    int k = t * 32 + (lane >> 4) * 8 + j;
    int n = u * 16 + (lane & 15);
    const float* W = (g < 11) ? (w1 + (size_t)g * 4096)
                  : (g < 15) ? (w2 + (size_t)(g - 11) * 4096) : wc;
    wf[idx] = __float2bfloat16(W[k * 64 + n]);
}

// zero pad row N of all nbuf g buffers
__global__ void zero_pads_kernel(__hip_bfloat16* __restrict__ gbase, size_t gstride,
                                 int nbuf, int N) {
    int i = blockIdx.x * blockDim.x + threadIdx.x;
    int b = i >> 6;
    if (b < nbuf) gbase[(size_t)b * gstride + (size_t)N * 64 + (i & 63)] = __float2bfloat16(0.0f);
}

// g0 = bf16(dinv ⊙ x)
__global__ void cvt_g_kernel(const float* __restrict__ x, const float* __restrict__ dinv,
                             __hip_bfloat16* __restrict__ g, int N) {
    int i = blockIdx.x * blockDim.x + threadIdx.x;
    if (i < N * 64) g[i] = __float2bfloat16(dinv[i >> 6] * x[i]);
}

// ---------------- propagation: pure gather hop ----------------
// One wave per dest. 8 B/lane gathers: each VMEM instruction loads 4 source
// rows x 128 B = 512 B. quad = lane>>4 picks the 4-src sub-group, c4 = lane&15
// the column group. srcs loads are NONTEMPORAL (sequential stream, don't evict
// g rows from L2). 2 shfl_xor rounds combine; quad0 stores the 128 B row.

__global__ __launch_bounds__(256) void hop_kernel(
        const __hip_bfloat16* __restrict__ g_in,
        const int* __restrict__ srcs, const int* __restrict__ rowptr,
        const float* __restrict__ dinv2,
        __hip_bfloat16* __restrict__ g_out, int n) {
    const int lane = threadIdx.x & 63;
    const int quad = lane >> 4;   // srcs sub-group 0..3
    const int c4 = lane & 15;     // column group: cols 4*c4 .. 4*c4+3
    int gw = __builtin_amdgcn_readfirstlane((blockIdx.x * blockDim.x + threadIdx.x) >> 6);
    int nw = (gridDim.x * blockDim.x) >> 6;
    for (int d = gw; d < n; d += nw) {
        int p0 = rowptr[d], p1 = rowptr[d + 1];
        float a0 = 0.f, a1 = 0.f, a2 = 0.f, a3 = 0.f;
        for (int p = p0; p < p1; p += 16) {
            const unsigned long long* ps = (const unsigned long long*)(srcs + p);
            unsigned long long s01 = __builtin_nontemporal_load(ps + quad * 2);
            unsigned long long s23 = __builtin_nontemporal_load(ps + quad * 2 + 1);
            int sx = (int)(s01 & 0xffffffffu), sy = (int)(s01 >> 32);
            int sz = (int)(s23 & 0xffffffffu), sw = (int)(s23 >> 32);
            uint2 v0 = ((const uint2*)(g_in + (size_t)sx * 64))[c4];
            uint2 v1 = ((const uint2*)(g_in + (size_t)sy * 64))[c4];
            uint2 v2 = ((const uint2*)(g_in + (size_t)sz * 64))[c4];
            uint2 v3 = ((const uint2*)(g_in + (size_t)sw * 64))[c4];
            a0 += __uint_as_float(v0.x << 16); a1 += __uint_as_float(v0.x & 0xffff0000u);
            a2 += __uint_as_float(v0.y << 16); a3 += __uint_as_float(v0.y & 0xffff0000u);
            a0 += __uint_as_float(v1.x << 16); a1 += __uint_as_float(v1.x & 0xffff0000u);
            a2 += __uint_as_float(v1.y << 16); a3 += __uint_as_float(v1.y & 0xffff0000u);
            a0 += __uint_as_float(v2.x << 16); a1 += __uint_as_float(v2.x & 0xffff0000u);
            a2 += __uint_as_float(v2.y << 16); a3 += __uint_as_float(v2.y & 0xffff0000u);
            a0 += __uint_as_float(v3.x << 16); a1 += __uint_as_float(v3.x & 0xffff0000u);
            a2 += __uint_as_float(v3.y << 16); a3 += __uint_as_float(v3.y & 0xffff0000u);
        }
        // combine the 4 srcs sub-groups: (g0+g1)+(g2+g3) per column
        a0 += __shfl_xor(a0, 16); a1 += __shfl_xor(a1, 16);
        a2 += __shfl_xor(a2, 16); a3 += __shfl_xor(a3, 16);
        a0 += __shfl_xor(a0, 32); a1 += __shfl_xor(a1, 32);
        a2 += __shfl_xor(a2, 32); a3 += __shfl_xor(a3, 32);
        if (quad == 0) {
            float s = dinv2[d];
            union { __hip_bfloat16 h[4]; uint2 u; } pk;
            pk.h[0] = __float2bfloat16(s * a0);
            pk.h[1] = __float2bfloat16(s * a1);
            pk.h[2] = __float2bfloat16(s * a2);
            pk.h[3] = __float2bfloat16(s * a3);
            ((uint2*)(g_out + (size_t)d * 64))[c4] = pk.u;
        }
    }
}

// ---------------- deferred multi-GEMM (MFMA) ----------------
// acc = sum_g G_g @ W_g ; tv = tanh(sdeg*acc + bias)
// out16 = bf16(scale * tv), scale = dinv (layer boundary) or 1 (pre-head v)
// Each wave handles FOUR adjacent 16-row tiles: W-fragment loads shared 4x,
// A-load MLP 4x. A-loads nontemporal (every G read here is last-use).
// #pragma unroll 1 on the g-loop (round-1 lesson: full unroll -> 212 VGPR).

template<int NG>
__global__ __launch_bounds__(256, 2) void final_kernel(
        const __hip_bfloat16* gbase, size_t gstride,
        const __hip_bfloat16* __restrict__ wf,
        const float* __restrict__ sdeg, const float* __restrict__ bias,
        const float* __restrict__ scale,
        __hip_bfloat16* out16, int ntiles) {
    const int lane = threadIdx.x & 63;
    const int col = lane & 15, quad = lane >> 4;
    int wv = (blockIdx.x * blockDim.x + threadIdx.x) >> 6;
    int nwv = (gridDim.x * blockDim.x) >> 6;
    const uint4v* wfq = (const uint4v*)wf;
    int nquads = (ntiles + 3) >> 2;
    for (int qd = wv; qd < nquads; qd += nwv) {
        int t0 = qd * 4;
        bool h1 = t0 + 1 < ntiles, h2 = t0 + 2 < ntiles, h3 = t0 + 3 < ntiles;
        int bA = t0 * 16;
        int bB = (h1 ? t0 + 1 : t0) * 16;
        int bC = (h2 ? t0 + 2 : t0) * 16;
        int bD = (h3 ? t0 + 3 : t0) * 16;
        float4v aA0 = {0,0,0,0}, aA1 = {0,0,0,0}, aA2 = {0,0,0,0}, aA3 = {0,0,0,0};
        float4v aB0 = {0,0,0,0}, aB1 = {0,0,0,0}, aB2 = {0,0,0,0}, aB3 = {0,0,0,0};
        float4v aC0 = {0,0,0,0}, aC1 = {0,0,0,0}, aC2 = {0,0,0,0}, aC3 = {0,0,0,0};
        float4v aD0 = {0,0,0,0}, aD1 = {0,0,0,0}, aD2 = {0,0,0,0}, aD3 = {0,0,0,0};
#pragma unroll 1
        for (int g = 0; g < NG; ++g) {
            const uint4v* ga = (const uint4v*)(gbase + (size_t)g * gstride);
            const uint4v* wg = wfq + (size_t)g * 512;
#pragma unroll
            for (int t = 0; t < 2; ++t) {
                int fo = t * 4 + quad;
                short8 fA = s8(__builtin_nontemporal_load(&ga[(size_t)(bA + col) * 8 + fo]));
                short8 fB = s8(__builtin_nontemporal_load(&ga[(size_t)(bB + col) * 8 + fo]));
                short8 fC = s8(__builtin_nontemporal_load(&ga[(size_t)(bC + col) * 8 + fo]));
                short8 fD = s8(__builtin_nontemporal_load(&ga[(size_t)(bD + col) * 8 + fo]));
                short8 w0 = s8(wg[(t * 4 + 0) * 64 + lane]);
                short8 w1 = s8(wg[(t * 4 + 1) * 64 + lane]);
                short8 w2 = s8(wg[(t * 4 + 2) * 64 + lane]);
                short8 w3 = s8(wg[(t * 4 + 3) * 64 + lane]);
                aA0 = __builtin_amdgcn_mfma_f32_16x16x32_bf16(fA, w0, aA0, 0, 0, 0);
                aB0 = __builtin_amdgcn_mfma_f32_16x16x32_bf16(fB, w0, aB0, 0, 0, 0);
                aC0 = __builtin_amdgcn_mfma_f32_16x16x32_bf16(fC, w0, aC0, 0, 0, 0);
                aD0 = __builtin_amdgcn_mfma_f32_16x16x32_bf16(fD, w0, aD0, 0, 0, 0);
                aA1 = __builtin_amdgcn_mfma_f32_16x16x32_bf16(fA, w1, aA1, 0, 0, 0);
                aB1 = __builtin_amdgcn_mfma_f32_16x16x32_bf16(fB, w1, aB1, 0, 0, 0);
                aC1 = __builtin_amdgcn_mfma_f32_16x16x32_bf16(fC, w1, aC1, 0, 0, 0);
                aD1 = __builtin_amdgcn_mfma_f32_16x16x32_bf16(fD, w1, aD1, 0, 0, 0);
                aA2 = __builtin_amdgcn_mfma_f32_16x16x32_bf16(fA, w2, aA2, 0, 0, 0);
                aB2 = __builtin_amdgcn_mfma_f32_16x16x32_bf16(fB, w2, aB2, 0, 0, 0);
                aC2 = __builtin_amdgcn_mfma_f32_16x16x32_bf16(fC, w2, aC2, 0, 0, 0);
                aD2 = __builtin_amdgcn_mfma_f32_16x16x32_bf16(fD, w2, aD2, 0, 0, 0);
                aA3 = __builtin_amdgcn_mfma_f32_16x16x32_bf16(fA, w3, aA3, 0, 0, 0);
                aB3 = __builtin_amdgcn_mfma_f32_16x16x32_bf16(fB, w3, aB3, 0, 0, 0);
                aC3 = __builtin_amdgcn_mfma_f32_16x16x32_bf16(fC, w3, aC3, 0, 0, 0);
                aD3 = __builtin_amdgcn_mfma_f32_16x16x32_bf16(fD, w3, aD3, 0, 0, 0);
            }
        }
        // epilogue helper via macro (static indexing only)
#define EPI(BASE, A0, A1, A2, A3)                                                    \
        {                                                                            \
            _Pragma("unroll")                                                        \
            for (int r = 0; r < 4; ++r) {                                            \
                int nd = (BASE) + quad * 4 + r;                                      \
                float sd = sdeg[nd];                                                 \
                float sc = scale ? scale[nd] : 1.0f;                                 \
                float f0 = sc * tanhf(sd * (A0)[r] + bias[0 * 16 + col]);            \
                float f1 = sc * tanhf(sd * (A1)[r] + bias[1 * 16 + col]);            \
                float f2 = sc * tanhf(sd * (A2)[r] + bias[2 * 16 + col]);            \
                float f3 = sc * tanhf(sd * (A3)[r] + bias[3 * 16 + col]);            \
                out16[(size_t)nd * 64 + 0 * 16 + col] = __float2bfloat16(f0);        \
                out16[(size_t)nd * 64 + 1 * 16 + col] = __float2bfloat16(f1);        \
                out16[(size_t)nd * 64 + 2 * 16 + col] = __float2bfloat16(f2);        \
                out16[(size_t)nd * 64 + 3 * 16 + col] = __float2bfloat16(f3);        \
            }                                                                        \
        }
        EPI(bA, aA0, aA1, aA2, aA3)
        if (h1) EPI(bB, aB0, aB1, aB2, aB3)
        if (h2) EPI(bC, aC0, aC1, aC2, aC3)
        if (h3) EPI(bD, aD0, aD1, aD2, aD3)
#undef EPI
    }
}

// ---------------- MFMA head: out = v16 @ Wc + bc ----------------

__global__ __launch_bounds__(256) void head_kernel(
        const __hip_bfloat16* __restrict__ v16, const __hip_bfloat16* __restrict__ wfc,
        const float* __restrict__ bc, float* __restrict__ out, int ntiles) {
    const int lane = threadIdx.x & 63;
    const int col = lane & 15, quad = lane >> 4;
    int wv = (blockIdx.x * blockDim.x + threadIdx.x) >> 6;
    int nwv = (gridDim.x * blockDim.x) >> 6;
    const uint4v* va = (const uint4v*)v16;
    const uint4v* wg = (const uint4v*)wfc;
    for (int tile = wv; tile < ntiles; tile += nwv) {
        int base = tile * 16;
        float4v acc0 = {0,0,0,0}, acc1 = {0,0,0,0}, acc2 = {0,0,0,0}, acc3 = {0,0,0,0};
#pragma unroll
        for (int t = 0; t < 2; ++t) {
            short8 a = s8(__builtin_nontemporal_load(&va[(size_t)(base + col) * 8 + t * 4 + quad]));
            short8 b0 = s8(wg[(t * 4 + 0) * 64 + lane]);
            short8 b1 = s8(wg[(t * 4 + 1) * 64 + lane]);
            short8 b2 = s8(wg[(t * 4 + 2) * 64 + lane]);
            short8 b3 = s8(wg[(t * 4 + 3) * 64 + lane]);
            acc0 = __builtin_amdgcn_mfma_f32_16x16x32_bf16(a, b0, acc0, 0, 0, 0);
            acc1 = __builtin_amdgcn_mfma_f32_16x16x32_bf16(a, b1, acc1, 0, 0, 0);
            acc2 = __builtin_amdgcn_mfma_f32_16x16x32_bf16(a, b2, acc2, 0, 0, 0);
            acc3 = __builtin_amdgcn_mfma_f32_16x16x32_bf16(a, b3, acc3, 0, 0, 0);
        }
#pragma unroll
        for (int r = 0; r < 4; ++r) {
            int nd = base + quad * 4 + r;
            out[(size_t)nd * 64 + 0 * 16 + col] = acc0[r] + bc[0 * 16 + col];
            out[(size_t)nd * 64 + 1 * 16 + col] = acc1[r] + bc[1 * 16 + col];
            out[(size_t)nd * 64 + 2 * 16 + col] = acc2[r] + bc[2 * 16 + col];
            out[(size_t)nd * 64 + 3 * 16 + col] = acc3[r] + bc[3 * 16 + col];
        }
    }
}

// ---------------- launch ----------------

extern "C" void kernel_launch(void* const* d_in, const int* in_sizes, int n_in,
                              void* d_out, int out_size, void* d_ws, size_t ws_size,
                              hipStream_t stream) {
    const float* x  = (const float*)d_in[0];
    const int*   ei = (const int*)d_in[1];   // [2, E] int32
    const float* w1 = (const float*)d_in[2]; // [11,64,64]
    const float* b1 = (const float*)d_in[3];
    const float* w2 = (const float*)d_in[4]; // [4,64,64]
    const float* b2 = (const float*)d_in[5];
    const float* wc = (const float*)d_in[6];
    const float* bc = (const float*)d_in[7];
    float* out = (float*)d_out;

    const int N = in_sizes[0] / 64;
    const int E = in_sizes[1] / 2;
    const int K1 = 10, K2 = 3;
    const int* row = ei;
    const int* col = ei + E;
    const int Epad = E + (PAD - 1) * N + 64;
    const int NBUF = 11;
    const int nbkt = (N + 511) >> 9;
    const size_t gstride = (((size_t)(N + 1) * 64) + 127) & ~(size_t)127;

    // workspace carve (256B aligned)
    char* base = (char*)d_ws;
    auto alloc = [&](size_t bytes) { void* p = (void*)base; base += (bytes + 255) & ~(size_t)255; return p; };
    int*   deg      = (int*)alloc((size_t)N * 4);
    int*   rowptr   = (int*)alloc((size_t)(N + 1) * 4);
    int*   chunkSum = (int*)alloc(256 * 4);
    int*   chunkOff = (int*)alloc(256 * 4);
    int*   blockHist= (int*)alloc((size_t)NBKT_MAX * 256 * 4);
    int*   bktTot   = (int*)alloc((size_t)NBKT_MAX * 4);
    int*   bktOff   = (int*)alloc((size_t)NBKT_MAX * 4);
    float* dinv     = (float*)alloc((size_t)N * 4);
    float* dinv2    = (float*)alloc((size_t)N * 4);
    float* sdeg     = (float*)alloc((size_t)N * 4);
    int*   srcs     = (int*)alloc((size_t)Epad * 4);
    __hip_bfloat16* wf    = (__hip_bfloat16*)alloc((size_t)16 * 4096 * 2);
    __hip_bfloat16* gbase = (__hip_bfloat16*)alloc((size_t)NBUF * gstride * 2);

    auto G = [&](int k) { return gbase + (size_t)k * gstride; };
    unsigned int* pairs = (unsigned int*)G(9);  // dead until hop 9; consumed before hops
    __hip_bfloat16* vbuf16 = G(5);              // free during layer-2 (hops use G(1..4))

    const int numChunks = (N + 511) / 512;      // == nbkt
    const int xBlocks = (N * 64 + 255) / 256;
    const int gBlocks = 2048;
    const int ntiles = (N + 15) / 16;
    const int nquads = (ntiles + 3) / 4;
    const int fBlocks = (nquads + 3) / 4;   // 4 waves/block, 1 tile-quad/wave
    const int hBlocks = (ntiles + 3) / 4;

    // ---- bucketed CSR build + degree ----
    hist_kernel<<<256, 256, 0, stream>>>(col, blockHist, E, nbkt);
    bscan_kernel<<<nbkt, 256, 0, stream>>>(blockHist, bktTot, nbkt);
    scan_small<<<1, 256, 0, stream>>>(bktTot, bktOff, nbkt);
    scatter_kernel<<<256, 256, 0, stream>>>(row, col, blockHist, bktOff, pairs, E, nbkt);
    deg_scanA_kernel<<<nbkt, 256, 0, stream>>>(pairs, bktOff, bktTot, deg, dinv, dinv2,
                                               sdeg, chunkSum, N);
    scan_small<<<1, 256, 0, stream>>>(chunkSum, chunkOff, numChunks);
    scan_phaseC<<<numChunks, 512, 0, stream>>>(deg, chunkOff, rowptr, N);
    cluster_kernel<<<nbkt, 256, 0, stream>>>(pairs, bktOff, bktTot, rowptr, srcs, N);

    wcvt_kernel<<<(16 * 4096 + 255) / 256, 256, 0, stream>>>(w1, w2, wc, wf);
    zero_pads_kernel<<<(NBUF * 64 + 255) / 256, 256, 0, stream>>>(gbase, gstride, NBUF, N);
    cvt_g_kernel<<<xBlocks, 256, 0, stream>>>(x, dinv, G(0), N);

    // ---- layer 1: 10 pure-gather hops: G(k-1) -> G(k) ----
    for (int k = 1; k <= K1; ++k)
        hop_kernel<<<gBlocks, 256, 0, stream>>>(G(k - 1), srcs, rowptr, dinv2, G(k), N);

    // ---- layer-1 GEMMs + tanh + next-layer g -> G(1) (tile-local overwrite: safe) ----
    final_kernel<11><<<fBlocks, 256, 0, stream>>>(gbase, gstride, wf, sdeg, b1, dinv,
                                                  G(1), ntiles);

    // ---- layer 2: 3 hops: G(1)->G(2)->G(3)->G(4) ----
    for (int k = 1; k <= K2; ++k)
        hop_kernel<<<gBlocks, 256, 0, stream>>>(G(k), srcs, rowptr, dinv2, G(k + 1), N);

    // ---- layer-2 GEMMs + tanh -> v16 (bf16) ----
    final_kernel<4><<<fBlocks, 256, 0, stream>>>(G(1), gstride, wf + (size_t)11 * 4096,
                                                 sdeg, b2, nullptr, vbuf16, ntiles);

    // ---- MFMA head: out = v16 @ wc + bc ----
    head_kernel<<<hBlocks, 256, 0, stream>>>(vbuf16, wf + (size_t)15 * 4096, bc, out, ntiles);
}

// Round 8
// 611.568 us; speedup vs baseline: 1.0884x; 1.0884x over previous
//
#include <hip/hip_runtime.h>
#include <hip/hip_bf16.h>

#define PAD 16        // pad each CSR segment to a multiple of 16 edges
#define NBKT_MAX 512  // buckets of 512 dests (dest >> 9)

typedef __attribute__((ext_vector_type(8))) short short8;
typedef __attribute__((ext_vector_type(4))) float float4v;

__device__ __forceinline__ short8 as_s8(uint4 v) {
    union { uint4 u; short8 s; } x; x.u = v; return x.s;
}

__device__ __forceinline__ int pad_up(int v) { return (v + (PAD - 1)) & ~(PAD - 1); }

// ---------------- bucketed CSR build ----------------
// pairs packed: (src << 9) | (dst & 511)  [src < 2^17, bucket-local dst 9 bits]

// per-block histogram of dest buckets; blockHist[bucket][block]; int4 reads
__global__ __launch_bounds__(256) void hist_kernel(const int* __restrict__ col,
                                                   int* __restrict__ blockHist, int E, int nbkt) {
    __shared__ int h[NBKT_MAX];
    for (int i = threadIdx.x; i < nbkt; i += 256) h[i] = 0;
    __syncthreads();
    int E4 = E >> 2;
    int stride = gridDim.x * 256;
    for (int i = blockIdx.x * 256 + threadIdx.x; i < E4; i += stride) {
        int4 c = ((const int4*)col)[i];
        atomicAdd(&h[c.x >> 9], 1);
        atomicAdd(&h[c.y >> 9], 1);
        atomicAdd(&h[c.z >> 9], 1);
        atomicAdd(&h[c.w >> 9], 1);
    }
    if (blockIdx.x == 0)
        for (int e = E4 * 4 + threadIdx.x; e < E; e += 256) atomicAdd(&h[col[e] >> 9], 1);
    __syncthreads();
    for (int i = threadIdx.x; i < nbkt; i += 256) blockHist[i * 256 + blockIdx.x] = h[i];
}

// per-bucket exclusive scan across the 256 blocks; bktTot[bucket] = total
__global__ __launch_bounds__(256) void bscan_kernel(int* __restrict__ blockHist,
                                                    int* __restrict__ bktTot, int nbkt) {
    __shared__ int a[256], b[256];
    int bkt = blockIdx.x;
    int t = threadIdx.x;
    int v = blockHist[bkt * 256 + t];
    a[t] = v;
    __syncthreads();
    int* s = a; int* d = b;
    for (int off = 1; off < 256; off <<= 1) {
        int x = s[t];
        if (t >= off) x += s[t - off];
        d[t] = x;
        __syncthreads();
        int* tmp = s; s = d; d = tmp;
    }
    blockHist[bkt * 256 + t] = s[t] - v;
    if (t == 255) bktTot[bkt] = s[t];
}

// generic single-block exclusive scan over n<=256 ints
__global__ void scan_small(const int* __restrict__ in, int* __restrict__ outp, int n) {
    __shared__ int a[256], b[256];
    int t = threadIdx.x;
    int v = t < n ? in[t] : 0;
    a[t] = v;
    __syncthreads();
    int* s = a; int* d = b;
    for (int off = 1; off < 256; off <<= 1) {
        int x = s[t];
        if (t >= off) x += s[t - off];
        d[t] = x;
        __syncthreads();
        int* tmp = s; s = d; d = tmp;
    }
    if (t < n) outp[t] = s[t] - v;
}

// scatter packed (src,dst) into bucket-grouped array; per-(block,bucket) runs contiguous
__global__ __launch_bounds__(256) void scatter_kernel(const int* __restrict__ row,
                                                      const int* __restrict__ col,
                                                      const int* __restrict__ blockHist,
                                                      const int* __restrict__ bktOff,
                                                      unsigned int* __restrict__ pairs,
                                                      int E, int nbkt) {
    __shared__ int cur[NBKT_MAX];
    for (int i = threadIdx.x; i < nbkt; i += 256)
        cur[i] = bktOff[i] + blockHist[i * 256 + blockIdx.x];
    __syncthreads();
    int E4 = E >> 2;
    int stride = gridDim.x * 256;
    for (int i = blockIdx.x * 256 + threadIdx.x; i < E4; i += stride) {
        int4 c = ((const int4*)col)[i];
        int4 r = ((const int4*)row)[i];
        int p0 = atomicAdd(&cur[c.x >> 9], 1);
        pairs[p0] = ((unsigned int)r.x << 9) | (unsigned int)(c.x & 511);
        int p1 = atomicAdd(&cur[c.y >> 9], 1);
        pairs[p1] = ((unsigned int)r.y << 9) | (unsigned int)(c.y & 511);
        int p2 = atomicAdd(&cur[c.z >> 9], 1);
        pairs[p2] = ((unsigned int)r.z << 9) | (unsigned int)(c.z & 511);
        int p3 = atomicAdd(&cur[c.w >> 9], 1);
        pairs[p3] = ((unsigned int)r.w << 9) | (unsigned int)(c.w & 511);
    }
    if (blockIdx.x == 0)
        for (int e = E4 * 4 + threadIdx.x; e < E; e += 256) {
            int dn = col[e];
            int p = atomicAdd(&cur[dn >> 9], 1);
            pairs[p] = ((unsigned int)row[e] << 9) | (unsigned int)(dn & 511);
        }
}

// fused: per-bucket degree histogram -> deg/dinv/dinv2/sdeg AND chunkSum (padded sums)
__global__ __launch_bounds__(256) void deg_scanA_kernel(
        const unsigned int* __restrict__ pairs, const int* __restrict__ bktOff,
        const int* __restrict__ bktTot,
        int* __restrict__ deg, float* __restrict__ dinv, float* __restrict__ dinv2,
        float* __restrict__ sdeg, int* __restrict__ chunkSum, int N) {
    __shared__ int cnt[512];
    __shared__ int wsum[4];
    int b = blockIdx.x, d0 = b << 9;
    int t = threadIdx.x;
    for (int i = t; i < 512; i += 256) cnt[i] = 0;
    __syncthreads();
    int lo = bktOff[b], hi = lo + bktTot[b];
    for (int p = lo + t; p < hi; p += 256)
        atomicAdd(&cnt[pairs[p] & 511u], 1);
    __syncthreads();
    int sA = 0;
    for (int i = t; i < 512; i += 256) {
        int c = cnt[i];
        sA += pad_up(c);
        int d = d0 + i;
        if (d < N) {
            deg[d] = c;
            float v = c > 0 ? rsqrtf((float)c) : 0.0f;
            dinv[d] = v;
            dinv2[d] = v * v;
            sdeg[d] = c > 0 ? sqrtf((float)c) : 0.0f;
        }
    }
    for (int o = 32; o > 0; o >>= 1) sA += __shfl_down(sA, o, 64);
    if ((t & 63) == 0) wsum[t >> 6] = sA;
    __syncthreads();
    if (t == 0) chunkSum[b] = wsum[0] + wsum[1] + wsum[2] + wsum[3];
}

__global__ void scan_phaseC(const int* __restrict__ deg, const int* __restrict__ chunkOff,
                            int* __restrict__ rowptr, int N) {
    __shared__ int a[512], b[512];
    int t = threadIdx.x;
    int idx = blockIdx.x * 512 + t;
    int v = idx < N ? pad_up(deg[idx]) : 0;
    a[t] = v;
    __syncthreads();
    int* s = a; int* d = b;
    for (int off = 1; off < 512; off <<= 1) {
        int x = s[t];
        if (t >= off) x += s[t - off];
        d[t] = x;
        __syncthreads();
        int* tmp = s; s = d; d = tmp;
    }
    if (idx < N) rowptr[idx] = chunkOff[blockIdx.x] + s[t] - v;
    if (idx == N - 1) rowptr[N] = chunkOff[blockIdx.x] + s[t];
}

// per-bucket: scatter srcs into the bucket's contiguous CSR window (L2-resident),
// then fill pad slots (cur[i] -> rowptr[d+1]) while the window is hot.
__global__ __launch_bounds__(256) void cluster_kernel(const unsigned int* __restrict__ pairs,
                                                      const int* __restrict__ bktOff,
                                                      const int* __restrict__ bktTot,
                                                      const int* __restrict__ rowptr,
                                                      int* __restrict__ srcs, int N) {
    __shared__ int cur[512];
    int b = blockIdx.x;
    int d0 = b << 9;
    for (int i = threadIdx.x; i < 512; i += 256) {
        int d = d0 + i;
        cur[i] = (d < N) ? rowptr[d] : 0;
    }
    __syncthreads();
    int lo = bktOff[b], hi = lo + bktTot[b];
    for (int p = lo + threadIdx.x; p < hi; p += 256) {
        unsigned int e = pairs[p];
        int pos = atomicAdd(&cur[e & 511u], 1);
        srcs[pos] = (int)(e >> 9);
    }
    __syncthreads();
    for (int i = threadIdx.x; i < 512; i += 256) {
        int d = d0 + i;
        if (d < N) {
            int p = cur[i];              // == rowptr[d] + deg[d]
            int p1 = rowptr[d + 1];
            for (; p < p1; ++p) srcs[p] = N;
        }
    }
}

// ---------------- weight conversion / g init ----------------

// Convert w1 (11) + w2 (4) + wc (1) into MFMA B-fragment order, bf16.
__global__ void wcvt_kernel(const float* __restrict__ w1, const float* __restrict__ w2,
                            const float* __restrict__ wc, __hip_bfloat16* __restrict__ wf) {
    int idx = blockIdx.x * blockDim.x + threadIdx.x;
    if (idx >= 16 * 4096) return;
    int g = idx >> 12, r = idx & 4095;
    int j = r & 7, lane = (r >> 3) & 63, u = (r >> 9) & 3, t = r >> 11;
    int k = t * 32 + (lane >> 4) * 8 + j;
    int n = u * 16 + (lane & 15);
    const float* W = (g < 11) ? (w1 + (size_t)g * 4096)
                  : (g < 15) ? (w2 + (size_t)(g - 11) * 4096) : wc;
    wf[idx] = __float2bfloat16(W[k * 64 + n]);
}

// zero pad row N of all nbuf g buffers
__global__ void zero_pads_kernel(__hip_bfloat16* __restrict__ gbase, size_t gstride,
                                 int nbuf, int N) {
    int i = blockIdx.x * blockDim.x + threadIdx.x;
    int b = i >> 6;
    if (b < nbuf) gbase[(size_t)b * gstride + (size_t)N * 64 + (i & 63)] = __float2bfloat16(0.0f);
}

// g0 = bf16(dinv ⊙ x)
__global__ void cvt_g_kernel(const float* __restrict__ x, const float* __restrict__ dinv,
                             __hip_bfloat16* __restrict__ g, int N) {
    int i = blockIdx.x * blockDim.x + threadIdx.x;
    if (i < N * 64) g[i] = __float2bfloat16(dinv[i >> 6] * x[i]);
}

// ---------------- propagation: pure gather hop (round-6 form: best measured) ----------------
// One wave per dest. 8 B/lane gathers: each VMEM instruction loads 4 source
// rows x 128 B = 512 B. quad = lane>>4 picks the 4-src sub-group, c4 = lane&15
// the column group. 2 shfl_xor rounds combine; quad0 stores the 128 B row.

__global__ __launch_bounds__(256) void hop_kernel(
        const __hip_bfloat16* __restrict__ g_in,
        const int* __restrict__ srcs, const int* __restrict__ rowptr,
        const float* __restrict__ dinv2,
        __hip_bfloat16* __restrict__ g_out, int n) {
    const int lane = threadIdx.x & 63;
    const int quad = lane >> 4;   // srcs sub-group 0..3
    const int c4 = lane & 15;     // column group: cols 4*c4 .. 4*c4+3
    int gw = __builtin_amdgcn_readfirstlane((blockIdx.x * blockDim.x + threadIdx.x) >> 6);
    int nw = (gridDim.x * blockDim.x) >> 6;
    for (int d = gw; d < n; d += nw) {
        int p0 = rowptr[d], p1 = rowptr[d + 1];
        float a0 = 0.f, a1 = 0.f, a2 = 0.f, a3 = 0.f;
        for (int p = p0; p < p1; p += 16) {
            int4 sq = ((const int4*)(srcs + p))[quad];
            const uint2* r0 = (const uint2*)(g_in + (size_t)sq.x * 64);
            const uint2* r1 = (const uint2*)(g_in + (size_t)sq.y * 64);
            const uint2* r2 = (const uint2*)(g_in + (size_t)sq.z * 64);
            const uint2* r3 = (const uint2*)(g_in + (size_t)sq.w * 64);
            uint2 v0 = r0[c4], v1 = r1[c4], v2 = r2[c4], v3 = r3[c4];
            a0 += __uint_as_float(v0.x << 16); a1 += __uint_as_float(v0.x & 0xffff0000u);
            a2 += __uint_as_float(v0.y << 16); a3 += __uint_as_float(v0.y & 0xffff0000u);
            a0 += __uint_as_float(v1.x << 16); a1 += __uint_as_float(v1.x & 0xffff0000u);
            a2 += __uint_as_float(v1.y << 16); a3 += __uint_as_float(v1.y & 0xffff0000u);
            a0 += __uint_as_float(v2.x << 16); a1 += __uint_as_float(v2.x & 0xffff0000u);
            a2 += __uint_as_float(v2.y << 16); a3 += __uint_as_float(v2.y & 0xffff0000u);
            a0 += __uint_as_float(v3.x << 16); a1 += __uint_as_float(v3.x & 0xffff0000u);
            a2 += __uint_as_float(v3.y << 16); a3 += __uint_as_float(v3.y & 0xffff0000u);
        }
        // combine the 4 srcs sub-groups: (g0+g1)+(g2+g3) per column
        a0 += __shfl_xor(a0, 16); a1 += __shfl_xor(a1, 16);
        a2 += __shfl_xor(a2, 16); a3 += __shfl_xor(a3, 16);
        a0 += __shfl_xor(a0, 32); a1 += __shfl_xor(a1, 32);
        a2 += __shfl_xor(a2, 32); a3 += __shfl_xor(a3, 32);
        if (quad == 0) {
            float s = dinv2[d];
            union { __hip_bfloat16 h[4]; uint2 u; } pk;
            pk.h[0] = __float2bfloat16(s * a0);
            pk.h[1] = __float2bfloat16(s * a1);
            pk.h[2] = __float2bfloat16(s * a2);
            pk.h[3] = __float2bfloat16(s * a3);
            ((uint2*)(g_out + (size_t)d * 64))[c4] = pk.u;
        }
    }
}

// ---------------- deferred multi-GEMM (MFMA) ----------------
// acc = sum_g G_g @ W_g ; tv = tanh(sdeg*acc + bias)
// out16 = bf16(scale * tv), scale = dinv (layer boundary) or 1 (pre-head v)
// Each wave handles TWO adjacent 16-row tiles (round-6 form: measured optimum
// over 1-tile [46.4] and 4-tile [43.5]): B-fragments shared, VGPR 44, Occ ~23%.

template<int NG>
__global__ __launch_bounds__(256, 4) void final_kernel(
        const __hip_bfloat16* gbase, size_t gstride,
        const __hip_bfloat16* __restrict__ wf,
        const float* __restrict__ sdeg, const float* __restrict__ bias,
        const float* __restrict__ scale,
        __hip_bfloat16* out16, int ntiles) {
    const int lane = threadIdx.x & 63;
    const int col = lane & 15, quad = lane >> 4;
    int wv = (blockIdx.x * blockDim.x + threadIdx.x) >> 6;
    int nwv = (gridDim.x * blockDim.x) >> 6;
    const uint4* wfq = (const uint4*)wf;
    int npairs = (ntiles + 1) >> 1;
    for (int pr = wv; pr < npairs; pr += nwv) {
        int tile1 = pr * 2;
        int tile2 = tile1 + 1;
        bool has2 = tile2 < ntiles;
        int ba = tile1 * 16;
        int bb = (has2 ? tile2 : tile1) * 16;
        float4v accA0 = {0.f, 0.f, 0.f, 0.f}, accA1 = {0.f, 0.f, 0.f, 0.f};
        float4v accA2 = {0.f, 0.f, 0.f, 0.f}, accA3 = {0.f, 0.f, 0.f, 0.f};
        float4v accB0 = {0.f, 0.f, 0.f, 0.f}, accB1 = {0.f, 0.f, 0.f, 0.f};
        float4v accB2 = {0.f, 0.f, 0.f, 0.f}, accB3 = {0.f, 0.f, 0.f, 0.f};
#pragma unroll 1
        for (int g = 0; g < NG; ++g) {
            const uint4* ga = (const uint4*)(gbase + (size_t)g * gstride);
            const uint4* wg = wfq + (size_t)g * 512;
#pragma unroll
            for (int t = 0; t < 2; ++t) {
                short8 aA = as_s8(ga[(size_t)(ba + col) * 8 + t * 4 + quad]);
                short8 aB = as_s8(ga[(size_t)(bb + col) * 8 + t * 4 + quad]);
                short8 w0 = as_s8(wg[(t * 4 + 0) * 64 + lane]);
                short8 w1 = as_s8(wg[(t * 4 + 1) * 64 + lane]);
                short8 w2 = as_s8(wg[(t * 4 + 2) * 64 + lane]);
                short8 w3 = as_s8(wg[(t * 4 + 3) * 64 + lane]);
                accA0 = __builtin_amdgcn_mfma_f32_16x16x32_bf16(aA, w0, accA0, 0, 0, 0);
                accB0 = __builtin_amdgcn_mfma_f32_16x16x32_bf16(aB, w0, accB0, 0, 0, 0);
                accA1 = __builtin_amdgcn_mfma_f32_16x16x32_bf16(aA, w1, accA1, 0, 0, 0);
                accB1 = __builtin_amdgcn_mfma_f32_16x16x32_bf16(aB, w1, accB1, 0, 0, 0);
                accA2 = __builtin_amdgcn_mfma_f32_16x16x32_bf16(aA, w2, accA2, 0, 0, 0);
                accB2 = __builtin_amdgcn_mfma_f32_16x16x32_bf16(aB, w2, accB2, 0, 0, 0);
                accA3 = __builtin_amdgcn_mfma_f32_16x16x32_bf16(aA, w3, accA3, 0, 0, 0);
                accB3 = __builtin_amdgcn_mfma_f32_16x16x32_bf16(aB, w3, accB3, 0, 0, 0);
            }
        }
#pragma unroll
        for (int r = 0; r < 4; ++r) {
            int nd = ba + quad * 4 + r;
            float sd = sdeg[nd];
            float sc = scale ? scale[nd] : 1.0f;
            float f0 = sc * tanhf(sd * accA0[r] + bias[0 * 16 + col]);
            float f1 = sc * tanhf(sd * accA1[r] + bias[1 * 16 + col]);
            float f2 = sc * tanhf(sd * accA2[r] + bias[2 * 16 + col]);
            float f3 = sc * tanhf(sd * accA3[r] + bias[3 * 16 + col]);
            out16[(size_t)nd * 64 + 0 * 16 + col] = __float2bfloat16(f0);
            out16[(size_t)nd * 64 + 1 * 16 + col] = __float2bfloat16(f1);
            out16[(size_t)nd * 64 + 2 * 16 + col] = __float2bfloat16(f2);
            out16[(size_t)nd * 64 + 3 * 16 + col] = __float2bfloat16(f3);
        }
        if (has2) {
#pragma unroll
            for (int r = 0; r < 4; ++r) {
                int nd = bb + quad * 4 + r;
                float sd = sdeg[nd];
                float sc = scale ? scale[nd] : 1.0f;
                float f0 = sc * tanhf(sd * accB0[r] + bias[0 * 16 + col]);
                float f1 = sc * tanhf(sd * accB1[r] + bias[1 * 16 + col]);
                float f2 = sc * tanhf(sd * accB2[r] + bias[2 * 16 + col]);
                float f3 = sc * tanhf(sd * accB3[r] + bias[3 * 16 + col]);
                out16[(size_t)nd * 64 + 0 * 16 + col] = __float2bfloat16(f0);
                out16[(size_t)nd * 64 + 1 * 16 + col] = __float2bfloat16(f1);
                out16[(size_t)nd * 64 + 2 * 16 + col] = __float2bfloat16(f2);
                out16[(size_t)nd * 64 + 3 * 16 + col] = __float2bfloat16(f3);
            }
        }
    }
}

// ---------------- MFMA head: out = v16 @ Wc + bc ----------------

__global__ __launch_bounds__(256) void head_kernel(
        const __hip_bfloat16* __restrict__ v16, const __hip_bfloat16* __restrict__ wfc,
        const float* __restrict__ bc, float* __restrict__ out, int ntiles) {
    const int lane = threadIdx.x & 63;
    const int col = lane & 15, quad = lane >> 4;
    int wv = (blockIdx.x * blockDim.x + threadIdx.x) >> 6;
    int nwv = (gridDim.x * blockDim.x) >> 6;
    const uint4* va = (const uint4*)v16;
    const uint4* wg = (const uint4*)wfc;
    for (int tile = wv; tile < ntiles; tile += nwv) {
        int base = tile * 16;
        float4v acc0 = {0.f, 0.f, 0.f, 0.f};
        float4v acc1 = {0.f, 0.f, 0.f, 0.f};
        float4v acc2 = {0.f, 0.f, 0.f, 0.f};
        float4v acc3 = {0.f, 0.f, 0.f, 0.f};
#pragma unroll
        for (int t = 0; t < 2; ++t) {
            short8 a = as_s8(va[(size_t)(base + col) * 8 + t * 4 + quad]);
            short8 b0 = as_s8(wg[(t * 4 + 0) * 64 + lane]);
            short8 b1 = as_s8(wg[(t * 4 + 1) * 64 + lane]);
            short8 b2 = as_s8(wg[(t * 4 + 2) * 64 + lane]);
            short8 b3 = as_s8(wg[(t * 4 + 3) * 64 + lane]);
            acc0 = __builtin_amdgcn_mfma_f32_16x16x32_bf16(a, b0, acc0, 0, 0, 0);
            acc1 = __builtin_amdgcn_mfma_f32_16x16x32_bf16(a, b1, acc1, 0, 0, 0);
            acc2 = __builtin_amdgcn_mfma_f32_16x16x32_bf16(a, b2, acc2, 0, 0, 0);
            acc3 = __builtin_amdgcn_mfma_f32_16x16x32_bf16(a, b3, acc3, 0, 0, 0);
        }
#pragma unroll
        for (int r = 0; r < 4; ++r) {
            int nd = base + quad * 4 + r;
            out[(size_t)nd * 64 + 0 * 16 + col] = acc0[r] + bc[0 * 16 + col];
            out[(size_t)nd * 64 + 1 * 16 + col] = acc1[r] + bc[1 * 16 + col];
            out[(size_t)nd * 64 + 2 * 16 + col] = acc2[r] + bc[2 * 16 + col];
            out[(size_t)nd * 64 + 3 * 16 + col] = acc3[r] + bc[3 * 16 + col];
        }
    }
}

// ---------------- launch ----------------

extern "C" void kernel_launch(void* const* d_in, const int* in_sizes, int n_in,
                              void* d_out, int out_size, void* d_ws, size_t ws_size,
                              hipStream_t stream) {
    const float* x  = (const float*)d_in[0];
    const int*   ei = (const int*)d_in[1];   // [2, E] int32
    const float* w1 = (const float*)d_in[2]; // [11,64,64]
    const float* b1 = (const float*)d_in[3];
    const float* w2 = (const float*)d_in[4]; // [4,64,64]
    const float* b2 = (const float*)d_in[5];
    const float* wc = (const float*)d_in[6];
    const float* bc = (const float*)d_in[7];
    float* out = (float*)d_out;

    const int N = in_sizes[0] / 64;
    const int E = in_sizes[1] / 2;
    const int K1 = 10, K2 = 3;
    const int* row = ei;
    const int* col = ei + E;
    const int Epad = E + (PAD - 1) * N + 64;
    const int NBUF = 11;
    const int nbkt = (N + 511) >> 9;
    const size_t gstride = (((size_t)(N + 1) * 64) + 127) & ~(size_t)127;

    // workspace carve (256B aligned)
    char* base = (char*)d_ws;
    auto alloc = [&](size_t bytes) { void* p = (void*)base; base += (bytes + 255) & ~(size_t)255; return p; };
    int*   deg      = (int*)alloc((size_t)N * 4);
    int*   rowptr   = (int*)alloc((size_t)(N + 1) * 4);
    int*   chunkSum = (int*)alloc(256 * 4);
    int*   chunkOff = (int*)alloc(256 * 4);
    int*   blockHist= (int*)alloc((size_t)NBKT_MAX * 256 * 4);
    int*   bktTot   = (int*)alloc((size_t)NBKT_MAX * 4);
    int*   bktOff   = (int*)alloc((size_t)NBKT_MAX * 4);
    float* dinv     = (float*)alloc((size_t)N * 4);
    float* dinv2    = (float*)alloc((size_t)N * 4);
    float* sdeg     = (float*)alloc((size_t)N * 4);
    int*   srcs     = (int*)alloc((size_t)Epad * 4);
    __hip_bfloat16* wf    = (__hip_bfloat16*)alloc((size_t)16 * 4096 * 2);
    __hip_bfloat16* gbase = (__hip_bfloat16*)alloc((size_t)NBUF * gstride * 2);

    auto G = [&](int k) { return gbase + (size_t)k * gstride; };
    unsigned int* pairs = (unsigned int*)G(9);  // dead until hop 9; consumed before hops
    __hip_bfloat16* vbuf16 = G(5);              // free during layer-2 (hops use G(1..4))

    const int numChunks = (N + 511) / 512;      // == nbkt
    const int xBlocks = (N * 64 + 255) / 256;
    const int gBlocks = 2048;
    const int ntiles = (N + 15) / 16;
    const int npairs = (ntiles + 1) / 2;
    const int fBlocks = (npairs + 3) / 4;   // 4 waves/block, 1 tile-pair/wave
    const int hBlocks = (ntiles + 3) / 4;

    // ---- bucketed CSR build + degree ----
    hist_kernel<<<256, 256, 0, stream>>>(col, blockHist, E, nbkt);
    bscan_kernel<<<nbkt, 256, 0, stream>>>(blockHist, bktTot, nbkt);
    scan_small<<<1, 256, 0, stream>>>(bktTot, bktOff, nbkt);
    scatter_kernel<<<256, 256, 0, stream>>>(row, col, blockHist, bktOff, pairs, E, nbkt);
    deg_scanA_kernel<<<nbkt, 256, 0, stream>>>(pairs, bktOff, bktTot, deg, dinv, dinv2,
                                               sdeg, chunkSum, N);
    scan_small<<<1, 256, 0, stream>>>(chunkSum, chunkOff, numChunks);
    scan_phaseC<<<numChunks, 512, 0, stream>>>(deg, chunkOff, rowptr, N);
    cluster_kernel<<<nbkt, 256, 0, stream>>>(pairs, bktOff, bktTot, rowptr, srcs, N);

    wcvt_kernel<<<(16 * 4096 + 255) / 256, 256, 0, stream>>>(w1, w2, wc, wf);
    zero_pads_kernel<<<(NBUF * 64 + 255) / 256, 256, 0, stream>>>(gbase, gstride, NBUF, N);
    cvt_g_kernel<<<xBlocks, 256, 0, stream>>>(x, dinv, G(0), N);

    // ---- layer 1: 10 pure-gather hops: G(k-1) -> G(k) ----
    for (int k = 1; k <= K1; ++k)
        hop_kernel<<<gBlocks, 256, 0, stream>>>(G(k - 1), srcs, rowptr, dinv2, G(k), N);

    // ---- layer-1 GEMMs + tanh + next-layer g -> G(1) (tile-local overwrite: safe) ----
    final_kernel<11><<<fBlocks, 256, 0, stream>>>(gbase, gstride, wf, sdeg, b1, dinv,
                                                  G(1), ntiles);

    // ---- layer 2: 3 hops: G(1)->G(2)->G(3)->G(4) ----
    for (int k = 1; k <= K2; ++k)
        hop_kernel<<<gBlocks, 256, 0, stream>>>(G(k), srcs, rowptr, dinv2, G(k + 1), N);

    // ---- layer-2 GEMMs + tanh -> v16 (bf16) ----
    final_kernel<4><<<fBlocks, 256, 0, stream>>>(G(1), gstride, wf + (size_t)11 * 4096,
                                                 sdeg, b2, nullptr, vbuf16, ntiles);

    // ---- MFMA head: out = v16 @ wc + bc ----
    head_kernel<<<hBlocks, 256, 0, stream>>>(vbuf16, wf + (size_t)15 * 4096, bc, out, ntiles);
}